// Round 13
// baseline (462.991 us; speedup 1.0000x reference)
//
#include <hip/hip_runtime.h>
#include <hip/hip_bf16.h>

// Problem constants
#define NB_  16
#define NPTS 8192
#define NG   256
#define NP   (NB_*NPTS)   // 131072 points
#define NBLK (NP/64)      // 2048 fused5 blocks (M-tile 64)

// Output segment offsets (floats)
#define OFF_CENT 0
#define OFF_OUT  12288
#define OFF_PI   1060864
#define OFF_LAB  1454080

typedef unsigned short u16;
typedef __attribute__((ext_vector_type(8))) short bf16x8;
typedef __attribute__((ext_vector_type(4))) float f32x4;

// Workspace layout (bytes)
static constexpr size_t WS_SUMS  = 0;                                // B*G*4 f32
static constexpr size_t WS_A1    = 65536;                            // P*128 bf16 = 32MB (sorted)
static constexpr size_t WS_H     = WS_A1   + (size_t)NP*128*2;       // P*256 bf16 = 64MB (sorted)
static constexpr size_t WS_PBF   = WS_H    + (size_t)NP*256*2;       // B*G*256 bf16 = 2MB
static constexpr size_t WS_WT1   = WS_PBF  + (size_t)NB_*NG*256*2;   // 256x128 bf16
static constexpr size_t WS_WT2A  = WS_WT1  + (size_t)256*128*2;      // 512x512 bf16
static constexpr size_t WS_WT2B  = WS_WT2A + (size_t)512*512*2;      // 256x512 bf16
static constexpr size_t WS_PREP  = WS_WT2B + (size_t)256*512*2;      // 4096x512 f32 = 8MB
static constexpr size_t WS_OFFS  = WS_PREP + (size_t)NB_*NG*512*4;   // 4096 i32
static constexpr size_t WS_CNT   = WS_OFFS + (size_t)NB_*NG*4;       // 4096 i32
static constexpr size_t WS_CUR   = WS_CNT  + (size_t)NB_*NG*4;       // 4096 i32
static constexpr size_t WS_SPOS  = WS_CUR  + (size_t)NB_*NG*4;       // NP i32
static constexpr size_t WS_GLAB  = WS_SPOS + (size_t)NP*4;           // NP i32
static constexpr size_t WS_PF    = WS_GLAB + (size_t)NP*4;           // NBLK*256 f32 = 2MB
static constexpr size_t WS_PL    = WS_PF   + (size_t)NBLK*256*4;     // NBLK*256 f32 = 2MB
static constexpr size_t WS_DST   = WS_PL   + (size_t)NBLK*256*4;     // B*G*256 f32 = 4MB
static constexpr size_t WS_NEED  = WS_DST  + (size_t)NB_*NG*256*4;   // ~121 MB

__device__ __forceinline__ u16 f2bf_bits(float f){
  __hip_bfloat16 h = __float2bfloat16(f);
  union { __hip_bfloat16 h; u16 s; } u; u.h = h; return u.s;
}
__device__ __forceinline__ float bf_bits2f(u16 s){
  return __uint_as_float(((unsigned)s) << 16);
}

// async global->LDS, 16B per lane. LDS dest must be wave-uniform base (lane*16 added by HW).
__device__ __forceinline__ void gload16(const void* g, void* l){
  __builtin_amdgcn_global_load_lds((const __attribute__((address_space(1))) void*)g,
                                   (__attribute__((address_space(3))) void*)l, 16, 0, 0);
}

// ---------------- init: zero sums + cursor ----------------
__global__ void k_init(float* __restrict__ sums, int* __restrict__ cursor){
  int i = blockIdx.x*blockDim.x + threadIdx.x;
  if (i < NB_*NG*4) sums[i] = 0.f;
  if (i < NB_*NG) cursor[i] = 0;
}

// ---------------- weight transpose+bf16: dst[n*K+k] = bf16(src[k*N+n]) ----------------
__global__ void k_wt(const float* __restrict__ src, u16* __restrict__ dst, int K, int N){
  int i = blockIdx.x*blockDim.x + threadIdx.x;
  if (i >= K*N) return;
  int n = i / K, k = i - n*K;
  dst[i] = f2bf_bits(src[(size_t)k*N + n]);
}

// ---------------- per-point pass 1: segment sums + labels-as-float ----------------
__global__ void k_points(const float* __restrict__ xyz, const int* __restrict__ labels,
                         float* __restrict__ sums, float* __restrict__ outLab){
  int p = blockIdx.x*blockDim.x + threadIdx.x;
  if (p >= NP) return;
  int b = p / NPTS;
  int g = labels[p];
  float x = xyz[p*3+0], y = xyz[p*3+1], z = xyz[p*3+2];
  float* s = sums + (size_t)(b*NG + g)*4;
  atomicAdd(s+0, x); atomicAdd(s+1, y); atomicAdd(s+2, z); atomicAdd(s+3, 1.f);
  outLab[p] = (float)g;
}

// ---------------- centroids ----------------
__global__ void k_cent(const float* __restrict__ sums, float* __restrict__ cent_out){
  int i = blockIdx.x*blockDim.x + threadIdx.x;   // b*G+g
  if (i >= NB_*NG) return;
  const float* s = sums + (size_t)i*4;
  float c = fmaxf(s[3], 1.f);
  cent_out[i*3+0] = s[0]/c;
  cent_out[i*3+1] = s[1]/c;
  cent_out[i*3+2] = s[2]/c;
}

// ---------------- exclusive scan of counts per batch -> offs (absolute), counts ----------------
__global__ void k_scan(const float* __restrict__ sums, int* __restrict__ offs,
                       int* __restrict__ counts){
  __shared__ int sc[256];
  int b = blockIdx.x, g = threadIdx.x;
  int c = (int)(sums[(size_t)(b*NG+g)*4+3] + 0.5f);
  sc[g] = c;
  __syncthreads();
  for (int d = 1; d < 256; d <<= 1){
    int t = (g >= d) ? sc[g-d] : 0;
    __syncthreads();
    sc[g] += t;
    __syncthreads();
  }
  offs[b*NG+g] = b*NPTS + sc[g] - c;   // exclusive, absolute row index
  counts[b*NG+g] = c;
}

// ---------------- scatter: sorted position per point; sorted labels ----------------
__global__ void k_scatter(const int* __restrict__ labels, const int* __restrict__ offs,
                          int* __restrict__ cursor, int* __restrict__ sortpos,
                          int* __restrict__ glab){
  int p = blockIdx.x*blockDim.x + threadIdx.x;
  if (p >= NP) return;
  int b = p / NPTS, g = labels[p];
  int pos = offs[b*NG+g] + atomicAdd(&cursor[b*NG+g], 1);
  sortpos[p] = pos;
  glab[pos] = g;
}

// ---------------- MLP1 front: rel@w1a+b1a -> LN -> ReLU -> a1 (bf16, SORTED), also p_i ----
__global__ __launch_bounds__(256) void k_mlp1(
    const float* __restrict__ xyz, const int* __restrict__ labels,
    const int* __restrict__ sortpos, const float* __restrict__ cent,
    const float* __restrict__ w1a, const float* __restrict__ b1a,
    const float* __restrict__ g1, const float* __restrict__ beta1,
    u16* __restrict__ a1, float* __restrict__ pi_out)
{
  int wave = (int)((blockIdx.x*blockDim.x + threadIdx.x) >> 6);
  int lane = threadIdx.x & 63;
  int p = wave;
  if (p >= NP) return;
  int b = p / NPTS;
  int g = labels[p];
  const float* cb = cent + (size_t)(b*NG+g)*3;
  float c0 = cb[0], c1 = cb[1], c2 = cb[2];
  float r0 = xyz[p*3+0]-c0, r1 = xyz[p*3+1]-c1, r2 = xyz[p*3+2]-c2;
  if (lane < 3) pi_out[(size_t)p*3+lane] = (lane==0?c0:(lane==1?c1:c2));
  int j = lane*2;
  float2 wa0 = *(const float2*)(w1a + 0*128 + j);
  float2 wa1 = *(const float2*)(w1a + 1*128 + j);
  float2 wa2 = *(const float2*)(w1a + 2*128 + j);
  float2 bb  = *(const float2*)(b1a + j);
  float t0 = bb.x + r0*wa0.x + r1*wa1.x + r2*wa2.x;
  float t1 = bb.y + r0*wa0.y + r1*wa1.y + r2*wa2.y;
  float s = t0+t1, sq = t0*t0 + t1*t1;
  #pragma unroll
  for (int m = 32; m; m >>= 1){ s += __shfl_xor(s, m); sq += __shfl_xor(sq, m); }
  float mu  = s * (1.f/128.f);
  float var = sq * (1.f/128.f) - mu*mu;
  float inv = rsqrtf(var + 1e-5f);
  float2 gg = *(const float2*)(g1 + j), be = *(const float2*)(beta1 + j);
  float a0 = fmaxf((t0-mu)*inv*gg.x + be.x, 0.f);
  float a1v = fmaxf((t1-mu)*inv*gg.y + be.y, 0.f);
  unsigned pk = ((unsigned)f2bf_bits(a1v) << 16) | f2bf_bits(a0);
  int sp = sortpos[p];
  *reinterpret_cast<unsigned*>(a1 + (size_t)sp*128 + j) = pk;
}

// ---------------- MFMA bf16 GEMM (generic): C[M][Nc] = A@B + bias ----------------
// EPI 1: bf16 store;  EPI 3: f32 store (Cf).  No atomics.
template<int EPI>
__global__ __launch_bounds__(256)
void mgemm(const u16* __restrict__ A, int lda, int K,
           const u16* __restrict__ BT, int ldb, int kofs,
           const float* __restrict__ bias,
           u16* __restrict__ Cst, float* __restrict__ Cf, int ldc, int Nc)
{
  __shared__ alignas(16) u16 As[128*32];
  __shared__ alignas(16) u16 Bs[128*32];
  int NBk = Nc >> 7;
  int bm = blockIdx.x / NBk, bn = blockIdx.x % NBk;
  int m0 = bm << 7, n0 = bn << 7;
  int tid = threadIdx.x;
  int lane = tid & 63, w = tid >> 6;
  int wr = w >> 1, wc = w & 1;
  int l15 = lane & 15, l4 = lane >> 4;
  int r0 = tid >> 2;
  int ks = (tid & 3) << 3;
  u16* asd0 = As + (size_t)(w*64)*8;
  u16* asd1 = As + (size_t)(256 + w*64)*8;
  u16* bsd0 = Bs + (size_t)(w*64)*8;
  u16* bsd1 = Bs + (size_t)(256 + w*64)*8;
  f32x4 acc[4][4];
  #pragma unroll
  for (int i = 0; i < 4; ++i)
    #pragma unroll
    for (int jj = 0; jj < 4; ++jj)
      #pragma unroll
      for (int e = 0; e < 4; ++e) acc[i][jj][e] = 0.f;

  for (int k0 = 0; k0 < K; k0 += 32){
    gload16(A + (size_t)(m0 + r0)*lda + k0 + ks, asd0);
    gload16(A + (size_t)(m0 + r0 + 64)*lda + k0 + ks, asd1);
    gload16(BT + (size_t)(n0 + r0)*ldb + kofs + k0 + ks, bsd0);
    gload16(BT + (size_t)(n0 + r0 + 64)*ldb + kofs + k0 + ks, bsd1);
    __syncthreads();
    bf16x8 af[4], bfr[4];
    #pragma unroll
    for (int i = 0; i < 4; ++i){
      af[i]  = *(const bf16x8*)&As[(size_t)(wr*64 + i*16 + l15)*32 + l4*8];
      bfr[i] = *(const bf16x8*)&Bs[(size_t)(wc*64 + i*16 + l15)*32 + l4*8];
    }
    #pragma unroll
    for (int i = 0; i < 4; ++i)
      #pragma unroll
      for (int jj = 0; jj < 4; ++jj)
        acc[i][jj] = __builtin_amdgcn_mfma_f32_16x16x32_bf16(af[i], bfr[jj], acc[i][jj], 0, 0, 0);
    __syncthreads();
  }

  float bi[4];
  #pragma unroll
  for (int jj = 0; jj < 4; ++jj) bi[jj] = bias[n0 + wc*64 + jj*16 + l15];
  #pragma unroll
  for (int i = 0; i < 4; ++i){
    #pragma unroll
    for (int r = 0; r < 4; ++r){
      int m = m0 + wr*64 + i*16 + l4*4 + r;
      #pragma unroll
      for (int jj = 0; jj < 4; ++jj){
        int n = n0 + wc*64 + jj*16 + l15;
        float v = acc[i][jj][r] + bi[jj];
        if (EPI == 1) Cst[(size_t)m*ldc + n] = f2bf_bits(v);
        if (EPI == 3) Cf[(size_t)m*ldc + n] = v;
      }
    }
  }
}

// ---------------- pool: per-group streaming max over sorted h -> poolbf ----------------
__global__ __launch_bounds__(256) void k_pool(const u16* __restrict__ h,
                                              const int* __restrict__ offs,
                                              const int* __restrict__ counts,
                                              u16* __restrict__ poolbf){
  int bg = blockIdx.x, c = threadIdx.x;
  int cnt = counts[bg];
  if (cnt == 0){ poolbf[(size_t)bg*256 + c] = 0; return; }   // bf16 +0
  int off = offs[bg];
  float mx = bf_bits2f(h[(size_t)off*256 + c]);
  for (int r = 1; r < cnt; ++r)
    mx = fmaxf(mx, bf_bits2f(h[(size_t)(off+r)*256 + c]));
  poolbf[(size_t)bg*256 + c] = f2bf_bits(mx);
}

// ---------------- fused5: u = h@W2a_bot + prep[gather] ; LN+ReLU ; v = u@w2b ; seg-partials ----
// M-tile 64, 1024 threads = 16 waves (wave grid 2M x 8N). Halved per-wave register
// state (acc[2][4] phase1, acc2[2][2] phase2) so total VGPR+AGPR <= 128 ->
// 4 waves/SIMD from one resident block (r12 lesson: rocprof VGPR_Count excludes
// AGPRs; fused4's 104+64 ~= 168 regs allowed only 2 waves/SIMD -> latency-bound).
// Barrier-free K-loops; h staged once (2 gload16/wave); weights direct global->reg.
__global__ __launch_bounds__(1024, 1)
void fused5(const u16* __restrict__ h, const u16* __restrict__ wt2a,
            const u16* __restrict__ wt2b, const float* __restrict__ prepf,
            const float* __restrict__ b2b, const float* __restrict__ g2,
            const float* __restrict__ beta2, const int* __restrict__ glab,
            float* __restrict__ pf, float* __restrict__ pl, float* __restrict__ dstage)
{
  __shared__ alignas(16) char smem[66560];
  float* ssum  = (float*)(smem + 65536);   // [64]
  float* ssq   = (float*)(smem + 65792);   // [64]
  int*  glab_s = (int*)(smem + 66048);     // [64]
  int tid = threadIdx.x;
  int w = tid >> 6, lane = tid & 63;
  int wm = w >> 3, wn = w & 7;
  int l15 = lane & 15, l4 = lane >> 4;
  int m0 = blockIdx.x << 6;
  if (tid < 64){ ssum[tid] = 0.f; ssq[tid] = 0.f; glab_s[tid] = glab[m0 + tid]; }

  // ---- stage h tile [64 rows][512B] -> LDS once; swizzled source, linear dest ----
  // 32 insts of 1KB (2 rows each); wave w issues q = 2w, 2w+1.
  {
    const char* hb = (const char*)h;
    int lrow = lane >> 5;             // 0/1 within inst
    int kb = (lane & 31) << 4;        // byte col 0..496
    #pragma unroll
    for (int t = 0; t < 2; ++t){
      int q = w*2 + t;
      int row = q*2 + lrow;
      gload16(hb + (size_t)(m0 + row)*512 + (kb ^ ((row & 7) << 4)),
              smem + q*1024);
    }
  }
  f32x4 acc[2][4];
  #pragma unroll
  for (int i = 0; i < 2; ++i)
    #pragma unroll
    for (int j = 0; j < 4; ++j)
      #pragma unroll
      for (int e = 0; e < 4; ++e) acc[i][j][e] = 0.f;
  __syncthreads();   // h staged (drains vmcnt), ssum/ssq/glab_s ready

  // ---- phase 1 (barrier-free): acc = h_tile @ W2a_bot, B direct from global ----
  {
    const u16* wA = wt2a + ((size_t)((wn<<6) + l15))*512 + 256 + l4*8;  // + j*8192 + k
    #pragma unroll
    for (int kk = 0; kk < 8; ++kk){
      const int k0 = kk*32;
      bf16x8 af[2], bfr[4];
      #pragma unroll
      for (int i = 0; i < 2; ++i){
        int row = (wm<<5) + (i<<4) + l15;
        af[i] = *(const bf16x8*)(smem + row*512 + ((((k0 + l4*8)) << 1) ^ ((row & 7) << 4)));
      }
      #pragma unroll
      for (int j = 0; j < 4; ++j)
        bfr[j] = *(const bf16x8*)(wA + j*8192 + k0);
      #pragma unroll
      for (int i = 0; i < 2; ++i)
        #pragma unroll
        for (int j = 0; j < 4; ++j)
          acc[i][j] = __builtin_amdgcn_mfma_f32_16x16x32_bf16(af[i], bfr[j], acc[i][j], 0, 0, 0);
    }
  }

  // ---- phase 1.5: + prep gather, LN stats, normalize+ReLU, u -> LDS (swizzled) ----
  int gb = (m0 / NPTS) * NG;
  {
    int grp[2][4];
    #pragma unroll
    for (int i = 0; i < 2; ++i)
      #pragma unroll
      for (int r = 0; r < 4; ++r)
        grp[i][r] = gb + glab_s[(wm<<5) + (i<<4) + (l4<<2) + r];
    #pragma unroll
    for (int i = 0; i < 2; ++i)
      #pragma unroll
      for (int j = 0; j < 4; ++j){
        int n = (wn<<6) + (j<<4) + l15;
        #pragma unroll
        for (int r = 0; r < 4; ++r)
          acc[i][j][r] += prepf[((size_t)grp[i][r] << 9) + n];
      }
  }
  #pragma unroll
  for (int i = 0; i < 2; ++i)
    #pragma unroll
    for (int r = 0; r < 4; ++r){
      float s = 0.f, q = 0.f;
      #pragma unroll
      for (int j = 0; j < 4; ++j){ float v = acc[i][j][r]; s += v; q += v*v; }
      #pragma unroll
      for (int mk = 1; mk < 16; mk <<= 1){ s += __shfl_xor(s, mk); q += __shfl_xor(q, mk); }
      if (l15 == 0){
        int row = (wm<<5) + (i<<4) + (l4<<2) + r;
        atomicAdd(&ssum[row], s);
        atomicAdd(&ssq[row], q);
      }
    }
  __syncthreads();   // also: all h reads complete
  if (tid < 64){
    float mu = ssum[tid] * (1.f/512.f);
    float var = ssq[tid] * (1.f/512.f) - mu*mu;
    ssum[tid] = mu;
    ssq[tid] = rsqrtf(var + 1e-5f);
  }
  __syncthreads();
  {
    float gcol[4], bcol[4];
    #pragma unroll
    for (int j = 0; j < 4; ++j){
      int n = (wn<<6) + (j<<4) + l15;
      gcol[j] = g2[n]; bcol[j] = beta2[n];
    }
    #pragma unroll
    for (int i = 0; i < 2; ++i)
      #pragma unroll
      for (int r = 0; r < 4; ++r){
        int row = (wm<<5) + (i<<4) + (l4<<2) + r;
        float mu = ssum[row], inv = ssq[row];
        #pragma unroll
        for (int j = 0; j < 4; ++j){
          int n = (wn<<6) + (j<<4) + l15;
          float v = fmaxf((acc[i][j][r] - mu)*inv*gcol[j] + bcol[j], 0.f);
          int byo = (row << 10) + (((n << 1)) ^ ((row & 7) << 4));
          *(u16*)(smem + byo) = f2bf_bits(v);
        }
      }
  }
  __syncthreads();   // u complete

  // ---- phase 2 (barrier-free): v = u_lds @ w2b, B direct from global ----
  f32x4 acc2[2][2];
  #pragma unroll
  for (int i = 0; i < 2; ++i)
    #pragma unroll
    for (int j = 0; j < 2; ++j)
      #pragma unroll
      for (int e = 0; e < 4; ++e) acc2[i][j][e] = 0.f;

  {
    const u16* wB = wt2b + ((size_t)((wn<<5) + l15))*512 + l4*8;  // + j*8192 + k
    #pragma unroll
    for (int kk = 0; kk < 16; ++kk){
      const int k0 = kk*32;
      bf16x8 af2[2], bf2[2];
      #pragma unroll
      for (int i = 0; i < 2; ++i){
        int row = (wm<<5) + (i<<4) + l15;
        af2[i] = *(const bf16x8*)(smem + (row << 10) + ((((k0 + l4*8)) << 1) ^ ((row & 7) << 4)));
      }
      #pragma unroll
      for (int j = 0; j < 2; ++j)
        bf2[j] = *(const bf16x8*)(wB + j*8192 + k0);
      #pragma unroll
      for (int i = 0; i < 2; ++i)
        #pragma unroll
        for (int j = 0; j < 2; ++j)
          acc2[i][j] = __builtin_amdgcn_mfma_f32_16x16x32_bf16(af2[i], bf2[j], acc2[i][j], 0, 0, 0);
    }
  }
  __syncthreads();   // all u reads done before vbuf overwrite

  // ---- epilogue: v -> vbuf [64][256] f32 (aliases u), per-channel segment walk ----
  float bb0 = b2b[(wn<<5) + l15], bb1 = b2b[(wn<<5) + 16 + l15];
  float* vbuf = (float*)smem;
  #pragma unroll
  for (int i = 0; i < 2; ++i)
    #pragma unroll
    for (int j = 0; j < 2; ++j){
      int n = (wn<<5) + (j<<4) + l15;
      float bbj = j ? bb1 : bb0;
      #pragma unroll
      for (int r = 0; r < 4; ++r){
        int row = (wm<<5) + (i<<4) + (l4<<2) + r;
        vbuf[row*256 + n] = acc2[i][j][r] + bbj;
      }
    }
  __syncthreads();
  if (tid < 256){
    int c = tid;
    size_t blk = blockIdx.x;
    int curg = glab_s[0];
    float mx = vbuf[c];
    bool from0 = true;
    for (int r = 1; r < 64; ++r){
      int g = glab_s[r];
      float v = vbuf[r*256 + c];
      if (g != curg){
        if (from0) pf[blk*256 + c] = mx;
        else       dstage[((size_t)(gb + curg))*256 + c] = mx;
        curg = g; mx = v; from0 = false;
      } else mx = fmaxf(mx, v);
    }
    if (from0) pf[blk*256 + c] = mx;
    else       pl[blk*256 + c] = mx;
  }
}

// ---------------- combine: out[bg] = max over block partials (deterministic) ----------------
__global__ __launch_bounds__(256) void k_combine(const int* __restrict__ offs,
                                                 const int* __restrict__ counts,
                                                 const float* __restrict__ pf,
                                                 const float* __restrict__ pl,
                                                 const float* __restrict__ dstage,
                                                 float* __restrict__ outp){
  int bg = blockIdx.x, c = threadIdx.x;
  int cnt = counts[bg];
  if (cnt == 0){ outp[(size_t)bg*256 + c] = 0.f; return; }
  int off = offs[bg], end = off + cnt;
  int B0 = off >> 6, B1 = (end - 1) >> 6;
  float v;
  if (B0 == B1){
    if ((off & 63) == 0)      v = pf[(size_t)B0*256 + c];
    else if ((end & 63) == 0) v = pl[(size_t)B0*256 + c];
    else                      v = dstage[(size_t)bg*256 + c];
  } else {
    v = ((off & 63) == 0) ? pf[(size_t)B0*256 + c] : pl[(size_t)B0*256 + c];
    for (int k = B0 + 1; k <= B1; ++k)
      v = fmaxf(v, pf[(size_t)k*256 + c]);
  }
  outp[(size_t)bg*256 + c] = v;
}

// ---------------- ws-too-small signal ----------------
__global__ void k_sig(float* __restrict__ out, float val){
  int i = blockIdx.x*blockDim.x + threadIdx.x;
  if (i < 256) out[i] = val;
}

extern "C" void kernel_launch(void* const* d_in, const int* in_sizes, int n_in,
                              void* d_out, int out_size, void* d_ws, size_t ws_size,
                              hipStream_t stream) {
  const float* xyz    = (const float*)d_in[0];
  const int*   labels = (const int*)  d_in[1];
  const float* w1a    = (const float*)d_in[2];
  const float* b1a    = (const float*)d_in[3];
  const float* g1     = (const float*)d_in[4];
  const float* beta1  = (const float*)d_in[5];
  const float* w1b    = (const float*)d_in[6];
  const float* b1b    = (const float*)d_in[7];
  const float* w2a    = (const float*)d_in[8];
  const float* b2a    = (const float*)d_in[9];
  const float* g2     = (const float*)d_in[10];
  const float* beta2  = (const float*)d_in[11];
  const float* w2b    = (const float*)d_in[12];
  const float* b2b    = (const float*)d_in[13];
  float* out = (float*)d_out;
  char* ws = (char*)d_ws;

  if (ws_size < WS_NEED){
    k_sig<<<1, 256, 0, stream>>>(out, 10000.f + (float)(ws_size >> 20));
    return;
  }

  float*     sums   = (float*)(ws + WS_SUMS);
  u16*       a1     = (u16*)(ws + WS_A1);
  u16*       h      = (u16*)(ws + WS_H);
  u16*       poolbf = (u16*)(ws + WS_PBF);
  u16*       wt1    = (u16*)(ws + WS_WT1);
  u16*       wt2a   = (u16*)(ws + WS_WT2A);
  u16*       wt2b   = (u16*)(ws + WS_WT2B);
  float*     prepf  = (float*)(ws + WS_PREP);
  int*       offs   = (int*)(ws + WS_OFFS);
  int*       counts = (int*)(ws + WS_CNT);
  int*       cursor = (int*)(ws + WS_CUR);
  int*       sortpos= (int*)(ws + WS_SPOS);
  int*       glab   = (int*)(ws + WS_GLAB);
  float*     pf     = (float*)(ws + WS_PF);
  float*     pl     = (float*)(ws + WS_PL);
  float*     dstage = (float*)(ws + WS_DST);

  float* cent_out = out + OFF_CENT;
  float* out_seg  = out + OFF_OUT;
  float* pi_out   = out + OFF_PI;
  float* lab_out  = out + OFF_LAB;

  k_init<<<64, 256, 0, stream>>>(sums, cursor);
  k_wt<<<(128*256+255)/256, 256, 0, stream>>>(w1b, wt1, 128, 256);
  k_wt<<<(512*512+255)/256, 256, 0, stream>>>(w2a, wt2a, 512, 512);
  k_wt<<<(512*256+255)/256, 256, 0, stream>>>(w2b, wt2b, 512, 256);
  k_points<<<NP/256, 256, 0, stream>>>(xyz, labels, sums, lab_out);
  k_cent<<<(NB_*NG+255)/256, 256, 0, stream>>>(sums, cent_out);
  k_scan<<<NB_, 256, 0, stream>>>(sums, offs, counts);
  k_scatter<<<NP/256, 256, 0, stream>>>(labels, offs, cursor, sortpos, glab);
  k_mlp1<<<NP/4, 256, 0, stream>>>(xyz, labels, sortpos, cent_out,
                                   w1a, b1a, g1, beta1, a1, pi_out);
  // GEMM1: h = a1 @ w1b + b1b (sorted rows); bf16 store
  mgemm<1><<<(NP/128)*(256/128), 256, 0, stream>>>(
      a1, 128, 128, wt1, 128, 0, b1b, h, (float*)nullptr, 256, 256);
  // pool: per-group max over sorted h -> poolbf
  k_pool<<<NB_*NG, 256, 0, stream>>>(h, offs, counts, poolbf);
  // prep = poolbf @ w2a[0:256,:] + b2a : [B*G, 512] f32
  mgemm<3><<<(NB_*NG/128)*(512/128), 256, 0, stream>>>(
      poolbf, 256, 256, wt2a, 512, 0, b2a, (u16*)nullptr, prepf, 512, 512);
  // fused5: GEMM2a' + LN + GEMM2b -> block partial maxes
  fused5<<<NBLK, 1024, 0, stream>>>(h, wt2a, wt2b, prepf, b2b, g2, beta2, glab,
                                    pf, pl, dstage);
  // combine partials -> out
  k_combine<<<NB_*NG, 256, 0, stream>>>(offs, counts, pf, pl, dstage, out_seg);
}

// Round 14
// 371.170 us; speedup vs baseline: 1.2474x; 1.2474x over previous
//
#include <hip/hip_runtime.h>
#include <hip/hip_bf16.h>

// Problem constants
#define NB_  16
#define NPTS 8192
#define NG   256
#define NP   (NB_*NPTS)   // 131072 points
#define NBLK (NP/128)     // 1024 fused6 blocks (M-tile 128)

// Output segment offsets (floats)
#define OFF_CENT 0
#define OFF_OUT  12288
#define OFF_PI   1060864
#define OFF_LAB  1454080

typedef unsigned short u16;
typedef __attribute__((ext_vector_type(8))) short bf16x8;
typedef __attribute__((ext_vector_type(4))) float f32x4;

// Workspace layout (bytes)
static constexpr size_t WS_SUMS  = 0;                                // B*G*4 f32
static constexpr size_t WS_A1    = 65536;                            // P*128 bf16 = 32MB (sorted)
static constexpr size_t WS_H     = WS_A1   + (size_t)NP*128*2;       // P*256 bf16 = 64MB (sorted)
static constexpr size_t WS_PBF   = WS_H    + (size_t)NP*256*2;       // B*G*256 bf16 = 2MB
static constexpr size_t WS_WT1   = WS_PBF  + (size_t)NB_*NG*256*2;   // 256x128 bf16
static constexpr size_t WS_WT2A  = WS_WT1  + (size_t)256*128*2;      // 512x512 bf16
static constexpr size_t WS_WT2B  = WS_WT2A + (size_t)512*512*2;      // 256x512 bf16
static constexpr size_t WS_PREP  = WS_WT2B + (size_t)256*512*2;      // 4096x512 f32 = 8MB
static constexpr size_t WS_OFFS  = WS_PREP + (size_t)NB_*NG*512*4;   // 4096 i32
static constexpr size_t WS_CNT   = WS_OFFS + (size_t)NB_*NG*4;       // 4096 i32
static constexpr size_t WS_CUR   = WS_CNT  + (size_t)NB_*NG*4;       // 4096 i32
static constexpr size_t WS_SPOS  = WS_CUR  + (size_t)NB_*NG*4;       // NP i32
static constexpr size_t WS_GLAB  = WS_SPOS + (size_t)NP*4;           // NP i32
static constexpr size_t WS_PF    = WS_GLAB + (size_t)NP*4;           // NBLK*256 f32 = 1MB
static constexpr size_t WS_PL    = WS_PF   + (size_t)NBLK*256*4;     // NBLK*256 f32 = 1MB
static constexpr size_t WS_DST   = WS_PL   + (size_t)NBLK*256*4;     // B*G*256 f32 = 4MB
static constexpr size_t WS_NEED  = WS_DST  + (size_t)NB_*NG*256*4;   // ~119 MB

__device__ __forceinline__ u16 f2bf_bits(float f){
  __hip_bfloat16 h = __float2bfloat16(f);
  union { __hip_bfloat16 h; u16 s; } u; u.h = h; return u.s;
}
__device__ __forceinline__ float bf_bits2f(u16 s){
  return __uint_as_float(((unsigned)s) << 16);
}

// async global->LDS, 16B per lane. LDS dest must be wave-uniform base (lane*16 added by HW).
__device__ __forceinline__ void gload16(const void* g, void* l){
  __builtin_amdgcn_global_load_lds((const __attribute__((address_space(1))) void*)g,
                                   (__attribute__((address_space(3))) void*)l, 16, 0, 0);
}

// ---------------- init: zero sums + cursor ----------------
__global__ void k_init(float* __restrict__ sums, int* __restrict__ cursor){
  int i = blockIdx.x*blockDim.x + threadIdx.x;
  if (i < NB_*NG*4) sums[i] = 0.f;
  if (i < NB_*NG) cursor[i] = 0;
}

// ---------------- weight transpose+bf16: dst[n*K+k] = bf16(src[k*N+n]) ----------------
__global__ void k_wt(const float* __restrict__ src, u16* __restrict__ dst, int K, int N){
  int i = blockIdx.x*blockDim.x + threadIdx.x;
  if (i >= K*N) return;
  int n = i / K, k = i - n*K;
  dst[i] = f2bf_bits(src[(size_t)k*N + n]);
}

// ---------------- per-point pass 1: segment sums + labels-as-float ----------------
__global__ void k_points(const float* __restrict__ xyz, const int* __restrict__ labels,
                         float* __restrict__ sums, float* __restrict__ outLab){
  int p = blockIdx.x*blockDim.x + threadIdx.x;
  if (p >= NP) return;
  int b = p / NPTS;
  int g = labels[p];
  float x = xyz[p*3+0], y = xyz[p*3+1], z = xyz[p*3+2];
  float* s = sums + (size_t)(b*NG + g)*4;
  atomicAdd(s+0, x); atomicAdd(s+1, y); atomicAdd(s+2, z); atomicAdd(s+3, 1.f);
  outLab[p] = (float)g;
}

// ---------------- centroids ----------------
__global__ void k_cent(const float* __restrict__ sums, float* __restrict__ cent_out){
  int i = blockIdx.x*blockDim.x + threadIdx.x;   // b*G+g
  if (i >= NB_*NG) return;
  const float* s = sums + (size_t)i*4;
  float c = fmaxf(s[3], 1.f);
  cent_out[i*3+0] = s[0]/c;
  cent_out[i*3+1] = s[1]/c;
  cent_out[i*3+2] = s[2]/c;
}

// ---------------- exclusive scan of counts per batch -> offs (absolute), counts ----------------
__global__ void k_scan(const float* __restrict__ sums, int* __restrict__ offs,
                       int* __restrict__ counts){
  __shared__ int sc[256];
  int b = blockIdx.x, g = threadIdx.x;
  int c = (int)(sums[(size_t)(b*NG+g)*4+3] + 0.5f);
  sc[g] = c;
  __syncthreads();
  for (int d = 1; d < 256; d <<= 1){
    int t = (g >= d) ? sc[g-d] : 0;
    __syncthreads();
    sc[g] += t;
    __syncthreads();
  }
  offs[b*NG+g] = b*NPTS + sc[g] - c;   // exclusive, absolute row index
  counts[b*NG+g] = c;
}

// ---------------- scatter: sorted position per point; sorted labels ----------------
__global__ void k_scatter(const int* __restrict__ labels, const int* __restrict__ offs,
                          int* __restrict__ cursor, int* __restrict__ sortpos,
                          int* __restrict__ glab){
  int p = blockIdx.x*blockDim.x + threadIdx.x;
  if (p >= NP) return;
  int b = p / NPTS, g = labels[p];
  int pos = offs[b*NG+g] + atomicAdd(&cursor[b*NG+g], 1);
  sortpos[p] = pos;
  glab[pos] = g;
}

// ---------------- MLP1 front: rel@w1a+b1a -> LN -> ReLU -> a1 (bf16, SORTED), also p_i ----
__global__ __launch_bounds__(256) void k_mlp1(
    const float* __restrict__ xyz, const int* __restrict__ labels,
    const int* __restrict__ sortpos, const float* __restrict__ cent,
    const float* __restrict__ w1a, const float* __restrict__ b1a,
    const float* __restrict__ g1, const float* __restrict__ beta1,
    u16* __restrict__ a1, float* __restrict__ pi_out)
{
  int wave = (int)((blockIdx.x*blockDim.x + threadIdx.x) >> 6);
  int lane = threadIdx.x & 63;
  int p = wave;
  if (p >= NP) return;
  int b = p / NPTS;
  int g = labels[p];
  const float* cb = cent + (size_t)(b*NG+g)*3;
  float c0 = cb[0], c1 = cb[1], c2 = cb[2];
  float r0 = xyz[p*3+0]-c0, r1 = xyz[p*3+1]-c1, r2 = xyz[p*3+2]-c2;
  if (lane < 3) pi_out[(size_t)p*3+lane] = (lane==0?c0:(lane==1?c1:c2));
  int j = lane*2;
  float2 wa0 = *(const float2*)(w1a + 0*128 + j);
  float2 wa1 = *(const float2*)(w1a + 1*128 + j);
  float2 wa2 = *(const float2*)(w1a + 2*128 + j);
  float2 bb  = *(const float2*)(b1a + j);
  float t0 = bb.x + r0*wa0.x + r1*wa1.x + r2*wa2.x;
  float t1 = bb.y + r0*wa0.y + r1*wa1.y + r2*wa2.y;
  float s = t0+t1, sq = t0*t0 + t1*t1;
  #pragma unroll
  for (int m = 32; m; m >>= 1){ s += __shfl_xor(s, m); sq += __shfl_xor(sq, m); }
  float mu  = s * (1.f/128.f);
  float var = sq * (1.f/128.f) - mu*mu;
  float inv = rsqrtf(var + 1e-5f);
  float2 gg = *(const float2*)(g1 + j), be = *(const float2*)(beta1 + j);
  float a0 = fmaxf((t0-mu)*inv*gg.x + be.x, 0.f);
  float a1v = fmaxf((t1-mu)*inv*gg.y + be.y, 0.f);
  unsigned pk = ((unsigned)f2bf_bits(a1v) << 16) | f2bf_bits(a0);
  int sp = sortpos[p];
  *reinterpret_cast<unsigned*>(a1 + (size_t)sp*128 + j) = pk;
}

// ---------------- MFMA bf16 GEMM (generic): C[M][Nc] = A@B + bias ----------------
// EPI 1: bf16 store;  EPI 3: f32 store (Cf).  No atomics.
template<int EPI>
__global__ __launch_bounds__(256)
void mgemm(const u16* __restrict__ A, int lda, int K,
           const u16* __restrict__ BT, int ldb, int kofs,
           const float* __restrict__ bias,
           u16* __restrict__ Cst, float* __restrict__ Cf, int ldc, int Nc)
{
  __shared__ alignas(16) u16 As[128*32];
  __shared__ alignas(16) u16 Bs[128*32];
  int NBk = Nc >> 7;
  int bm = blockIdx.x / NBk, bn = blockIdx.x % NBk;
  int m0 = bm << 7, n0 = bn << 7;
  int tid = threadIdx.x;
  int lane = tid & 63, w = tid >> 6;
  int wr = w >> 1, wc = w & 1;
  int l15 = lane & 15, l4 = lane >> 4;
  int r0 = tid >> 2;
  int ks = (tid & 3) << 3;
  u16* asd0 = As + (size_t)(w*64)*8;
  u16* asd1 = As + (size_t)(256 + w*64)*8;
  u16* bsd0 = Bs + (size_t)(w*64)*8;
  u16* bsd1 = Bs + (size_t)(256 + w*64)*8;
  f32x4 acc[4][4];
  #pragma unroll
  for (int i = 0; i < 4; ++i)
    #pragma unroll
    for (int jj = 0; jj < 4; ++jj)
      #pragma unroll
      for (int e = 0; e < 4; ++e) acc[i][jj][e] = 0.f;

  for (int k0 = 0; k0 < K; k0 += 32){
    gload16(A + (size_t)(m0 + r0)*lda + k0 + ks, asd0);
    gload16(A + (size_t)(m0 + r0 + 64)*lda + k0 + ks, asd1);
    gload16(BT + (size_t)(n0 + r0)*ldb + kofs + k0 + ks, bsd0);
    gload16(BT + (size_t)(n0 + r0 + 64)*ldb + kofs + k0 + ks, bsd1);
    __syncthreads();
    bf16x8 af[4], bfr[4];
    #pragma unroll
    for (int i = 0; i < 4; ++i){
      af[i]  = *(const bf16x8*)&As[(size_t)(wr*64 + i*16 + l15)*32 + l4*8];
      bfr[i] = *(const bf16x8*)&Bs[(size_t)(wc*64 + i*16 + l15)*32 + l4*8];
    }
    #pragma unroll
    for (int i = 0; i < 4; ++i)
      #pragma unroll
      for (int jj = 0; jj < 4; ++jj)
        acc[i][jj] = __builtin_amdgcn_mfma_f32_16x16x32_bf16(af[i], bfr[jj], acc[i][jj], 0, 0, 0);
    __syncthreads();
  }

  float bi[4];
  #pragma unroll
  for (int jj = 0; jj < 4; ++jj) bi[jj] = bias[n0 + wc*64 + jj*16 + l15];
  #pragma unroll
  for (int i = 0; i < 4; ++i){
    #pragma unroll
    for (int r = 0; r < 4; ++r){
      int m = m0 + wr*64 + i*16 + l4*4 + r;
      #pragma unroll
      for (int jj = 0; jj < 4; ++jj){
        int n = n0 + wc*64 + jj*16 + l15;
        float v = acc[i][jj][r] + bi[jj];
        if (EPI == 1) Cst[(size_t)m*ldc + n] = f2bf_bits(v);
        if (EPI == 3) Cf[(size_t)m*ldc + n] = v;
      }
    }
  }
}

// ---------------- pool: per-group streaming max over sorted h -> poolbf ----------------
__global__ __launch_bounds__(256) void k_pool(const u16* __restrict__ h,
                                              const int* __restrict__ offs,
                                              const int* __restrict__ counts,
                                              u16* __restrict__ poolbf){
  int bg = blockIdx.x, c = threadIdx.x;
  int cnt = counts[bg];
  if (cnt == 0){ poolbf[(size_t)bg*256 + c] = 0; return; }   // bf16 +0
  int off = offs[bg];
  float mx = bf_bits2f(h[(size_t)off*256 + c]);
  for (int r = 1; r < cnt; ++r)
    mx = fmaxf(mx, bf_bits2f(h[(size_t)(off+r)*256 + c]));
  poolbf[(size_t)bg*256 + c] = f2bf_bits(mx);
}

// ---------------- fused6: u = h@W2a_bot + prep[gather] ; LN+ReLU ; v = u@w2b ; seg-partials ----
// M-tile 128, 1024 threads = 16 waves in a 1M x 16N grid: each wave owns ALL 128 rows
// x a DISTINCT col slice (32 cols phase 1, 16 cols phase 2) -> zero duplicate weight
// reads (r13 lesson: wm-paired waves doubled L2 weight traffic); block count halves;
// 16 MFMA per L2 round-trip (af[8] from LDS, only bfr[2] from L2).
// LDS: h[128][256]=64KB staged once -> u[128][512]=128KB overwrites -> vbuf aliases u.
// __launch_bounds__(1024,1): 16 waves/CU = 4/SIMD -> VGPR cap 128 (acc 64 AGPR + ~50 VGPR).
__global__ __launch_bounds__(1024, 1)
void fused6(const u16* __restrict__ h, const u16* __restrict__ wt2a,
            const u16* __restrict__ wt2b, const float* __restrict__ prepf,
            const float* __restrict__ b2b, const float* __restrict__ g2,
            const float* __restrict__ beta2, const int* __restrict__ glab,
            float* __restrict__ pf, float* __restrict__ pl, float* __restrict__ dstage)
{
  __shared__ alignas(16) char smem[132608];
  float* ssum  = (float*)(smem + 131072);  // [128]
  float* ssq   = (float*)(smem + 131584);  // [128]
  int*  glab_s = (int*)(smem + 132096);    // [128]
  int tid = threadIdx.x;
  int w = tid >> 6, lane = tid & 63;
  int l15 = lane & 15, l4 = lane >> 4;
  int m0 = blockIdx.x << 7;
  if (tid < 128){ ssum[tid] = 0.f; ssq[tid] = 0.f; glab_s[tid] = glab[m0 + tid]; }

  // ---- stage h tile [128 rows][512B] -> LDS once; swizzled source, linear dest ----
  // 64 insts of 1KB (2 rows each); wave w issues q = w*4+t.
  {
    const char* hb = (const char*)h;
    int lrow = lane >> 5;             // 0/1 within inst
    int kb = (lane & 31) << 4;        // byte col 0..496
    #pragma unroll
    for (int t = 0; t < 4; ++t){
      int q = w*4 + t;
      int row = q*2 + lrow;
      gload16(hb + (size_t)(m0 + row)*512 + (kb ^ ((row & 7) << 4)),
              smem + q*1024);
    }
  }
  f32x4 acc[8][2];
  #pragma unroll
  for (int i = 0; i < 8; ++i)
    #pragma unroll
    for (int j = 0; j < 2; ++j)
      #pragma unroll
      for (int e = 0; e < 4; ++e) acc[i][j][e] = 0.f;
  __syncthreads();   // h staged (drains vmcnt), ssum/ssq/glab_s ready

  // ---- phase 1 (barrier-free): acc = h_tile @ W2a_bot; per wave 128 rows x 32 cols ----
  {
    const u16* wA = wt2a + ((size_t)((w<<5) + l15))*512 + 256 + l4*8;  // + j*8192 + k
    #pragma unroll
    for (int kk = 0; kk < 8; ++kk){
      const int k0 = kk*32;
      bf16x8 af[8], bfr[2];
      #pragma unroll
      for (int j = 0; j < 2; ++j)
        bfr[j] = *(const bf16x8*)(wA + j*8192 + k0);
      #pragma unroll
      for (int i = 0; i < 8; ++i){
        int row = (i<<4) + l15;
        af[i] = *(const bf16x8*)(smem + row*512 + ((((k0 + l4*8)) << 1) ^ ((row & 7) << 4)));
      }
      #pragma unroll
      for (int i = 0; i < 8; ++i)
        #pragma unroll
        for (int j = 0; j < 2; ++j)
          acc[i][j] = __builtin_amdgcn_mfma_f32_16x16x32_bf16(af[i], bfr[j], acc[i][j], 0, 0, 0);
    }
  }

  // ---- phase 1.5: + prep gather, LN stats, normalize+ReLU, u -> LDS (swizzled) ----
  int gb = (m0 / NPTS) * NG;
  #pragma unroll
  for (int i = 0; i < 8; ++i){
    #pragma unroll
    for (int r = 0; r < 4; ++r){
      int row = (i<<4) + (l4<<2) + r;
      int grp = gb + glab_s[row];
      #pragma unroll
      for (int j = 0; j < 2; ++j){
        int n = (w<<5) + (j<<4) + l15;
        acc[i][j][r] += prepf[((size_t)grp << 9) + n];
      }
    }
  }
  #pragma unroll
  for (int i = 0; i < 8; ++i)
    #pragma unroll
    for (int r = 0; r < 4; ++r){
      float s = 0.f, q = 0.f;
      #pragma unroll
      for (int j = 0; j < 2; ++j){ float v = acc[i][j][r]; s += v; q += v*v; }
      #pragma unroll
      for (int mk = 1; mk < 16; mk <<= 1){ s += __shfl_xor(s, mk); q += __shfl_xor(q, mk); }
      if (l15 == 0){
        int row = (i<<4) + (l4<<2) + r;
        atomicAdd(&ssum[row], s);
        atomicAdd(&ssq[row], q);
      }
    }
  __syncthreads();   // also: all h reads complete
  if (tid < 128){
    float mu = ssum[tid] * (1.f/512.f);
    float var = ssq[tid] * (1.f/512.f) - mu*mu;
    ssum[tid] = mu;
    ssq[tid] = rsqrtf(var + 1e-5f);
  }
  __syncthreads();
  {
    float gcol[2], bcol[2];
    #pragma unroll
    for (int j = 0; j < 2; ++j){
      int n = (w<<5) + (j<<4) + l15;
      gcol[j] = g2[n]; bcol[j] = beta2[n];
    }
    #pragma unroll
    for (int i = 0; i < 8; ++i)
      #pragma unroll
      for (int r = 0; r < 4; ++r){
        int row = (i<<4) + (l4<<2) + r;
        float mu = ssum[row], inv = ssq[row];
        #pragma unroll
        for (int j = 0; j < 2; ++j){
          int n = (w<<5) + (j<<4) + l15;
          float v = fmaxf((acc[i][j][r] - mu)*inv*gcol[j] + bcol[j], 0.f);
          int byo = (row << 10) + (((n << 1)) ^ ((row & 7) << 4));
          *(u16*)(smem + byo) = f2bf_bits(v);
        }
      }
  }
  __syncthreads();   // u complete

  // ---- phase 2 (barrier-free): v = u_lds @ w2b; per wave 128 rows x 16 cols ----
  f32x4 acc2[8];
  #pragma unroll
  for (int i = 0; i < 8; ++i)
    #pragma unroll
    for (int e = 0; e < 4; ++e) acc2[i][e] = 0.f;

  {
    const u16* wB = wt2b + ((size_t)((w<<4) + l15))*512 + l4*8;  // + k
    #pragma unroll
    for (int kk = 0; kk < 16; ++kk){
      const int k0 = kk*32;
      bf16x8 af2[8], bf2;
      bf2 = *(const bf16x8*)(wB + k0);
      #pragma unroll
      for (int i = 0; i < 8; ++i){
        int row = (i<<4) + l15;
        af2[i] = *(const bf16x8*)(smem + (row << 10) + ((((k0 + l4*8)) << 1) ^ ((row & 7) << 4)));
      }
      #pragma unroll
      for (int i = 0; i < 8; ++i)
        acc2[i] = __builtin_amdgcn_mfma_f32_16x16x32_bf16(af2[i], bf2, acc2[i], 0, 0, 0);
    }
  }
  __syncthreads();   // all u reads done before vbuf overwrite

  // ---- epilogue: v -> vbuf [128][256] f32 (aliases u), per-channel segment walk ----
  float bb = b2b[(w<<4) + l15];
  float* vbuf = (float*)smem;
  #pragma unroll
  for (int i = 0; i < 8; ++i){
    int n = (w<<4) + l15;
    #pragma unroll
    for (int r = 0; r < 4; ++r){
      int row = (i<<4) + (l4<<2) + r;
      vbuf[row*256 + n] = acc2[i][r] + bb;
    }
  }
  __syncthreads();
  if (tid < 256){
    int c = tid;
    size_t blk = blockIdx.x;
    int curg = glab_s[0];
    float mx = vbuf[c];
    bool from0 = true;
    for (int r = 1; r < 128; ++r){
      int g = glab_s[r];
      float v = vbuf[r*256 + c];
      if (g != curg){
        if (from0) pf[blk*256 + c] = mx;
        else       dstage[((size_t)(gb + curg))*256 + c] = mx;
        curg = g; mx = v; from0 = false;
      } else mx = fmaxf(mx, v);
    }
    if (from0) pf[blk*256 + c] = mx;
    else       pl[blk*256 + c] = mx;
  }
}

// ---------------- combine: out[bg] = max over block partials (deterministic) ----------------
__global__ __launch_bounds__(256) void k_combine(const int* __restrict__ offs,
                                                 const int* __restrict__ counts,
                                                 const float* __restrict__ pf,
                                                 const float* __restrict__ pl,
                                                 const float* __restrict__ dstage,
                                                 float* __restrict__ outp){
  int bg = blockIdx.x, c = threadIdx.x;
  int cnt = counts[bg];
  if (cnt == 0){ outp[(size_t)bg*256 + c] = 0.f; return; }
  int off = offs[bg], end = off + cnt;
  int B0 = off >> 7, B1 = (end - 1) >> 7;
  float v;
  if (B0 == B1){
    if ((off & 127) == 0)      v = pf[(size_t)B0*256 + c];
    else if ((end & 127) == 0) v = pl[(size_t)B0*256 + c];
    else                       v = dstage[(size_t)bg*256 + c];
  } else {
    v = ((off & 127) == 0) ? pf[(size_t)B0*256 + c] : pl[(size_t)B0*256 + c];
    for (int k = B0 + 1; k <= B1; ++k)
      v = fmaxf(v, pf[(size_t)k*256 + c]);
  }
  outp[(size_t)bg*256 + c] = v;
}

// ---------------- ws-too-small signal ----------------
__global__ void k_sig(float* __restrict__ out, float val){
  int i = blockIdx.x*blockDim.x + threadIdx.x;
  if (i < 256) out[i] = val;
}

extern "C" void kernel_launch(void* const* d_in, const int* in_sizes, int n_in,
                              void* d_out, int out_size, void* d_ws, size_t ws_size,
                              hipStream_t stream) {
  const float* xyz    = (const float*)d_in[0];
  const int*   labels = (const int*)  d_in[1];
  const float* w1a    = (const float*)d_in[2];
  const float* b1a    = (const float*)d_in[3];
  const float* g1     = (const float*)d_in[4];
  const float* beta1  = (const float*)d_in[5];
  const float* w1b    = (const float*)d_in[6];
  const float* b1b    = (const float*)d_in[7];
  const float* w2a    = (const float*)d_in[8];
  const float* b2a    = (const float*)d_in[9];
  const float* g2     = (const float*)d_in[10];
  const float* beta2  = (const float*)d_in[11];
  const float* w2b    = (const float*)d_in[12];
  const float* b2b    = (const float*)d_in[13];
  float* out = (float*)d_out;
  char* ws = (char*)d_ws;

  if (ws_size < WS_NEED){
    k_sig<<<1, 256, 0, stream>>>(out, 10000.f + (float)(ws_size >> 20));
    return;
  }

  float*     sums   = (float*)(ws + WS_SUMS);
  u16*       a1     = (u16*)(ws + WS_A1);
  u16*       h      = (u16*)(ws + WS_H);
  u16*       poolbf = (u16*)(ws + WS_PBF);
  u16*       wt1    = (u16*)(ws + WS_WT1);
  u16*       wt2a   = (u16*)(ws + WS_WT2A);
  u16*       wt2b   = (u16*)(ws + WS_WT2B);
  float*     prepf  = (float*)(ws + WS_PREP);
  int*       offs   = (int*)(ws + WS_OFFS);
  int*       counts = (int*)(ws + WS_CNT);
  int*       cursor = (int*)(ws + WS_CUR);
  int*       sortpos= (int*)(ws + WS_SPOS);
  int*       glab   = (int*)(ws + WS_GLAB);
  float*     pf     = (float*)(ws + WS_PF);
  float*     pl     = (float*)(ws + WS_PL);
  float*     dstage = (float*)(ws + WS_DST);

  float* cent_out = out + OFF_CENT;
  float* out_seg  = out + OFF_OUT;
  float* pi_out   = out + OFF_PI;
  float* lab_out  = out + OFF_LAB;

  k_init<<<64, 256, 0, stream>>>(sums, cursor);
  k_wt<<<(128*256+255)/256, 256, 0, stream>>>(w1b, wt1, 128, 256);
  k_wt<<<(512*512+255)/256, 256, 0, stream>>>(w2a, wt2a, 512, 512);
  k_wt<<<(512*256+255)/256, 256, 0, stream>>>(w2b, wt2b, 512, 256);
  k_points<<<NP/256, 256, 0, stream>>>(xyz, labels, sums, lab_out);
  k_cent<<<(NB_*NG+255)/256, 256, 0, stream>>>(sums, cent_out);
  k_scan<<<NB_, 256, 0, stream>>>(sums, offs, counts);
  k_scatter<<<NP/256, 256, 0, stream>>>(labels, offs, cursor, sortpos, glab);
  k_mlp1<<<NP/4, 256, 0, stream>>>(xyz, labels, sortpos, cent_out,
                                   w1a, b1a, g1, beta1, a1, pi_out);
  // GEMM1: h = a1 @ w1b + b1b (sorted rows); bf16 store
  mgemm<1><<<(NP/128)*(256/128), 256, 0, stream>>>(
      a1, 128, 128, wt1, 128, 0, b1b, h, (float*)nullptr, 256, 256);
  // pool: per-group max over sorted h -> poolbf
  k_pool<<<NB_*NG, 256, 0, stream>>>(h, offs, counts, poolbf);
  // prep = poolbf @ w2a[0:256,:] + b2a : [B*G, 512] f32
  mgemm<3><<<(NB_*NG/128)*(512/128), 256, 0, stream>>>(
      poolbf, 256, 256, wt2a, 512, 0, b2a, (u16*)nullptr, prepf, 512, 512);
  // fused6: GEMM2a' + LN + GEMM2b -> block partial maxes
  fused6<<<NBLK, 1024, 0, stream>>>(h, wt2a, wt2b, prepf, b2b, g2, beta2, glab,
                                    pf, pl, dstage);
  // combine partials -> out
  k_combine<<<NB_*NG, 256, 0, stream>>>(offs, counts, pf, pl, dstage, out_seg);
}

// Round 15
// 333.749 us; speedup vs baseline: 1.3872x; 1.1121x over previous
//
#include <hip/hip_runtime.h>
#include <hip/hip_bf16.h>

// Problem constants
#define NB_  16
#define NPTS 8192
#define NG   256
#define NP   (NB_*NPTS)   // 131072 points
#define NBLK (NP/128)     // 1024 fused6 blocks (M-tile 128)
#define NQ   (NP/32)      // 4096 32-row partial chunks

// Output segment offsets (floats)
#define OFF_CENT 0
#define OFF_OUT  12288
#define OFF_PI   1060864
#define OFF_LAB  1454080

typedef unsigned short u16;
typedef __attribute__((ext_vector_type(8))) short bf16x8;
typedef __attribute__((ext_vector_type(4))) float f32x4;

// Workspace layout (bytes)
static constexpr size_t WS_SUMS  = 0;                                // B*G*4 f32
static constexpr size_t WS_A1    = 65536;                            // P*128 bf16 = 32MB (sorted)
static constexpr size_t WS_H     = WS_A1   + (size_t)NP*128*2;       // P*256 bf16 = 64MB (sorted)
static constexpr size_t WS_PBF   = WS_H    + (size_t)NP*256*2;       // B*G*256 bf16 = 2MB
static constexpr size_t WS_WT1   = WS_PBF  + (size_t)NB_*NG*256*2;   // 256x128 bf16
static constexpr size_t WS_WT2A  = WS_WT1  + (size_t)256*128*2;      // 512x512 bf16
static constexpr size_t WS_WT2B  = WS_WT2A + (size_t)512*512*2;      // 256x512 bf16
static constexpr size_t WS_PREP  = WS_WT2B + (size_t)256*512*2;      // 4096x512 f32 = 8MB
static constexpr size_t WS_OFFS  = WS_PREP + (size_t)NB_*NG*512*4;   // 4096 i32
static constexpr size_t WS_CNT   = WS_OFFS + (size_t)NB_*NG*4;       // 4096 i32
static constexpr size_t WS_CUR   = WS_CNT  + (size_t)NB_*NG*4;       // 4096 i32
static constexpr size_t WS_SPOS  = WS_CUR  + (size_t)NB_*NG*4;       // NP i32
static constexpr size_t WS_GLAB  = WS_SPOS + (size_t)NP*4;           // NP i32
static constexpr size_t WS_PF    = WS_GLAB + (size_t)NP*4;           // NQ*256 f32 = 4MB
static constexpr size_t WS_PL    = WS_PF   + (size_t)NQ*256*4;       // NQ*256 f32 = 4MB
static constexpr size_t WS_DST   = WS_PL   + (size_t)NQ*256*4;       // B*G*256 f32 = 4MB
static constexpr size_t WS_NEED  = WS_DST  + (size_t)NB_*NG*256*4;   // ~125 MB

__device__ __forceinline__ u16 f2bf_bits(float f){
  __hip_bfloat16 h = __float2bfloat16(f);
  union { __hip_bfloat16 h; u16 s; } u; u.h = h; return u.s;
}
__device__ __forceinline__ float bf_bits2f(u16 s){
  return __uint_as_float(((unsigned)s) << 16);
}

// async global->LDS, 16B per lane. LDS dest must be wave-uniform base (lane*16 added by HW).
__device__ __forceinline__ void gload16(const void* g, void* l){
  __builtin_amdgcn_global_load_lds((const __attribute__((address_space(1))) void*)g,
                                   (__attribute__((address_space(3))) void*)l, 16, 0, 0);
}

// ---------------- init: zero sums + cursor ----------------
__global__ void k_init(float* __restrict__ sums, int* __restrict__ cursor){
  int i = blockIdx.x*blockDim.x + threadIdx.x;
  if (i < NB_*NG*4) sums[i] = 0.f;
  if (i < NB_*NG) cursor[i] = 0;
}

// ---------------- weight transpose+bf16: dst[n*K+k] = bf16(src[k*N+n]) ----------------
__global__ void k_wt(const float* __restrict__ src, u16* __restrict__ dst, int K, int N){
  int i = blockIdx.x*blockDim.x + threadIdx.x;
  if (i >= K*N) return;
  int n = i / K, k = i - n*K;
  dst[i] = f2bf_bits(src[(size_t)k*N + n]);
}

// ---------------- per-point pass 1: segment sums + labels-as-float ----------------
__global__ void k_points(const float* __restrict__ xyz, const int* __restrict__ labels,
                         float* __restrict__ sums, float* __restrict__ outLab){
  int p = blockIdx.x*blockDim.x + threadIdx.x;
  if (p >= NP) return;
  int b = p / NPTS;
  int g = labels[p];
  float x = xyz[p*3+0], y = xyz[p*3+1], z = xyz[p*3+2];
  float* s = sums + (size_t)(b*NG + g)*4;
  atomicAdd(s+0, x); atomicAdd(s+1, y); atomicAdd(s+2, z); atomicAdd(s+3, 1.f);
  outLab[p] = (float)g;
}

// ---------------- centroids ----------------
__global__ void k_cent(const float* __restrict__ sums, float* __restrict__ cent_out){
  int i = blockIdx.x*blockDim.x + threadIdx.x;   // b*G+g
  if (i >= NB_*NG) return;
  const float* s = sums + (size_t)i*4;
  float c = fmaxf(s[3], 1.f);
  cent_out[i*3+0] = s[0]/c;
  cent_out[i*3+1] = s[1]/c;
  cent_out[i*3+2] = s[2]/c;
}

// ---------------- exclusive scan of counts per batch -> offs (absolute), counts ----------------
__global__ void k_scan(const float* __restrict__ sums, int* __restrict__ offs,
                       int* __restrict__ counts){
  __shared__ int sc[256];
  int b = blockIdx.x, g = threadIdx.x;
  int c = (int)(sums[(size_t)(b*NG+g)*4+3] + 0.5f);
  sc[g] = c;
  __syncthreads();
  for (int d = 1; d < 256; d <<= 1){
    int t = (g >= d) ? sc[g-d] : 0;
    __syncthreads();
    sc[g] += t;
    __syncthreads();
  }
  offs[b*NG+g] = b*NPTS + sc[g] - c;   // exclusive, absolute row index
  counts[b*NG+g] = c;
}

// ---------------- scatter: sorted position per point; sorted labels ----------------
__global__ void k_scatter(const int* __restrict__ labels, const int* __restrict__ offs,
                          int* __restrict__ cursor, int* __restrict__ sortpos,
                          int* __restrict__ glab){
  int p = blockIdx.x*blockDim.x + threadIdx.x;
  if (p >= NP) return;
  int b = p / NPTS, g = labels[p];
  int pos = offs[b*NG+g] + atomicAdd(&cursor[b*NG+g], 1);
  sortpos[p] = pos;
  glab[pos] = g;
}

// ---------------- MLP1 front: rel@w1a+b1a -> LN -> ReLU -> a1 (bf16, SORTED), also p_i ----
__global__ __launch_bounds__(256) void k_mlp1(
    const float* __restrict__ xyz, const int* __restrict__ labels,
    const int* __restrict__ sortpos, const float* __restrict__ cent,
    const float* __restrict__ w1a, const float* __restrict__ b1a,
    const float* __restrict__ g1, const float* __restrict__ beta1,
    u16* __restrict__ a1, float* __restrict__ pi_out)
{
  int wave = (int)((blockIdx.x*blockDim.x + threadIdx.x) >> 6);
  int lane = threadIdx.x & 63;
  int p = wave;
  if (p >= NP) return;
  int b = p / NPTS;
  int g = labels[p];
  const float* cb = cent + (size_t)(b*NG+g)*3;
  float c0 = cb[0], c1 = cb[1], c2 = cb[2];
  float r0 = xyz[p*3+0]-c0, r1 = xyz[p*3+1]-c1, r2 = xyz[p*3+2]-c2;
  if (lane < 3) pi_out[(size_t)p*3+lane] = (lane==0?c0:(lane==1?c1:c2));
  int j = lane*2;
  float2 wa0 = *(const float2*)(w1a + 0*128 + j);
  float2 wa1 = *(const float2*)(w1a + 1*128 + j);
  float2 wa2 = *(const float2*)(w1a + 2*128 + j);
  float2 bb  = *(const float2*)(b1a + j);
  float t0 = bb.x + r0*wa0.x + r1*wa1.x + r2*wa2.x;
  float t1 = bb.y + r0*wa0.y + r1*wa1.y + r2*wa2.y;
  float s = t0+t1, sq = t0*t0 + t1*t1;
  #pragma unroll
  for (int m = 32; m; m >>= 1){ s += __shfl_xor(s, m); sq += __shfl_xor(sq, m); }
  float mu  = s * (1.f/128.f);
  float var = sq * (1.f/128.f) - mu*mu;
  float inv = rsqrtf(var + 1e-5f);
  float2 gg = *(const float2*)(g1 + j), be = *(const float2*)(beta1 + j);
  float a0 = fmaxf((t0-mu)*inv*gg.x + be.x, 0.f);
  float a1v = fmaxf((t1-mu)*inv*gg.y + be.y, 0.f);
  unsigned pk = ((unsigned)f2bf_bits(a1v) << 16) | f2bf_bits(a0);
  int sp = sortpos[p];
  *reinterpret_cast<unsigned*>(a1 + (size_t)sp*128 + j) = pk;
}

// ---------------- MFMA bf16 GEMM (generic): C[M][Nc] = A@B + bias ----------------
// EPI 1: bf16 store;  EPI 3: f32 store (Cf).  No atomics.
template<int EPI>
__global__ __launch_bounds__(256)
void mgemm(const u16* __restrict__ A, int lda, int K,
           const u16* __restrict__ BT, int ldb, int kofs,
           const float* __restrict__ bias,
           u16* __restrict__ Cst, float* __restrict__ Cf, int ldc, int Nc)
{
  __shared__ alignas(16) u16 As[128*32];
  __shared__ alignas(16) u16 Bs[128*32];
  int NBk = Nc >> 7;
  int bm = blockIdx.x / NBk, bn = blockIdx.x % NBk;
  int m0 = bm << 7, n0 = bn << 7;
  int tid = threadIdx.x;
  int lane = tid & 63, w = tid >> 6;
  int wr = w >> 1, wc = w & 1;
  int l15 = lane & 15, l4 = lane >> 4;
  int r0 = tid >> 2;
  int ks = (tid & 3) << 3;
  u16* asd0 = As + (size_t)(w*64)*8;
  u16* asd1 = As + (size_t)(256 + w*64)*8;
  u16* bsd0 = Bs + (size_t)(w*64)*8;
  u16* bsd1 = Bs + (size_t)(256 + w*64)*8;
  f32x4 acc[4][4];
  #pragma unroll
  for (int i = 0; i < 4; ++i)
    #pragma unroll
    for (int jj = 0; jj < 4; ++jj)
      #pragma unroll
      for (int e = 0; e < 4; ++e) acc[i][jj][e] = 0.f;

  for (int k0 = 0; k0 < K; k0 += 32){
    gload16(A + (size_t)(m0 + r0)*lda + k0 + ks, asd0);
    gload16(A + (size_t)(m0 + r0 + 64)*lda + k0 + ks, asd1);
    gload16(BT + (size_t)(n0 + r0)*ldb + kofs + k0 + ks, bsd0);
    gload16(BT + (size_t)(n0 + r0 + 64)*ldb + kofs + k0 + ks, bsd1);
    __syncthreads();
    bf16x8 af[4], bfr[4];
    #pragma unroll
    for (int i = 0; i < 4; ++i){
      af[i]  = *(const bf16x8*)&As[(size_t)(wr*64 + i*16 + l15)*32 + l4*8];
      bfr[i] = *(const bf16x8*)&Bs[(size_t)(wc*64 + i*16 + l15)*32 + l4*8];
    }
    #pragma unroll
    for (int i = 0; i < 4; ++i)
      #pragma unroll
      for (int jj = 0; jj < 4; ++jj)
        acc[i][jj] = __builtin_amdgcn_mfma_f32_16x16x32_bf16(af[i], bfr[jj], acc[i][jj], 0, 0, 0);
    __syncthreads();
  }

  float bi[4];
  #pragma unroll
  for (int jj = 0; jj < 4; ++jj) bi[jj] = bias[n0 + wc*64 + jj*16 + l15];
  #pragma unroll
  for (int i = 0; i < 4; ++i){
    #pragma unroll
    for (int r = 0; r < 4; ++r){
      int m = m0 + wr*64 + i*16 + l4*4 + r;
      #pragma unroll
      for (int jj = 0; jj < 4; ++jj){
        int n = n0 + wc*64 + jj*16 + l15;
        float v = acc[i][jj][r] + bi[jj];
        if (EPI == 1) Cst[(size_t)m*ldc + n] = f2bf_bits(v);
        if (EPI == 3) Cf[(size_t)m*ldc + n] = v;
      }
    }
  }
}

// ---------------- pool: per-group streaming max over sorted h -> poolbf ----------------
__global__ __launch_bounds__(256) void k_pool(const u16* __restrict__ h,
                                              const int* __restrict__ offs,
                                              const int* __restrict__ counts,
                                              u16* __restrict__ poolbf){
  int bg = blockIdx.x, c = threadIdx.x;
  int cnt = counts[bg];
  if (cnt == 0){ poolbf[(size_t)bg*256 + c] = 0; return; }   // bf16 +0
  int off = offs[bg];
  float mx = bf_bits2f(h[(size_t)off*256 + c]);
  for (int r = 1; r < cnt; ++r)
    mx = fmaxf(mx, bf_bits2f(h[(size_t)(off+r)*256 + c]));
  poolbf[(size_t)bg*256 + c] = f2bf_bits(mx);
}

// ---------------- fused6: u = h@W2a_bot + prep[gather] ; LN+ReLU ; v = u@w2b ; seg-partials ----
// M-tile 128, 1024 threads = 16 waves, 1M x 16N grid (no duplicate weight reads).
// r14 fixes: (1) af chunk-of-2 loads keep peak VGPR ~40 within the 64-VGPR budget
// (unified file: 64 AGPR acc + 64 VGPR = 128/wave at 4 waves/SIMD; af[8] spilled 99MB);
// (2) epilogue partial-max walk at 32-row QUARTER granularity so all 1024 threads
// participate (32 iters x4 parallel instead of 128 iters on 256 threads).
__global__ __launch_bounds__(1024, 1)
void fused6(const u16* __restrict__ h, const u16* __restrict__ wt2a,
            const u16* __restrict__ wt2b, const float* __restrict__ prepf,
            const float* __restrict__ b2b, const float* __restrict__ g2,
            const float* __restrict__ beta2, const int* __restrict__ glab,
            float* __restrict__ pf, float* __restrict__ pl, float* __restrict__ dstage)
{
  __shared__ alignas(16) char smem[132608];
  float* ssum  = (float*)(smem + 131072);  // [128]
  float* ssq   = (float*)(smem + 131584);  // [128]
  int*  glab_s = (int*)(smem + 132096);    // [128]
  int tid = threadIdx.x;
  int w = tid >> 6, lane = tid & 63;
  int l15 = lane & 15, l4 = lane >> 4;
  int m0 = blockIdx.x << 7;
  if (tid < 128){ ssum[tid] = 0.f; ssq[tid] = 0.f; glab_s[tid] = glab[m0 + tid]; }

  // ---- stage h tile [128 rows][512B] -> LDS once; swizzled source, linear dest ----
  {
    const char* hb = (const char*)h;
    int lrow = lane >> 5;             // 0/1 within inst
    int kb = (lane & 31) << 4;        // byte col 0..496
    #pragma unroll
    for (int t = 0; t < 4; ++t){
      int q = w*4 + t;
      int row = q*2 + lrow;
      gload16(hb + (size_t)(m0 + row)*512 + (kb ^ ((row & 7) << 4)),
              smem + q*1024);
    }
  }
  f32x4 acc[8][2];
  #pragma unroll
  for (int i = 0; i < 8; ++i)
    #pragma unroll
    for (int j = 0; j < 2; ++j)
      #pragma unroll
      for (int e = 0; e < 4; ++e) acc[i][j][e] = 0.f;
  __syncthreads();   // h staged (drains vmcnt), ssum/ssq/glab_s ready

  // ---- phase 1 (barrier-free): acc = h_tile @ W2a_bot; per wave 128 rows x 32 cols ----
  // af loaded in chunks of 2 (8 VGPR live) to stay within the 64-VGPR budget.
  {
    const u16* wA = wt2a + ((size_t)((w<<5) + l15))*512 + 256 + l4*8;  // + j*8192 + k
    #pragma unroll
    for (int kk = 0; kk < 8; ++kk){
      const int k0 = kk*32;
      bf16x8 bfr[2];
      #pragma unroll
      for (int j = 0; j < 2; ++j)
        bfr[j] = *(const bf16x8*)(wA + j*8192 + k0);
      #pragma unroll
      for (int ip = 0; ip < 4; ++ip){
        bf16x8 af0, af1;
        {
          int row0 = ((2*ip)<<4) + l15;
          int row1 = ((2*ip+1)<<4) + l15;
          af0 = *(const bf16x8*)(smem + row0*512 + ((((k0 + l4*8)) << 1) ^ ((row0 & 7) << 4)));
          af1 = *(const bf16x8*)(smem + row1*512 + ((((k0 + l4*8)) << 1) ^ ((row1 & 7) << 4)));
        }
        #pragma unroll
        for (int j = 0; j < 2; ++j){
          acc[2*ip][j]   = __builtin_amdgcn_mfma_f32_16x16x32_bf16(af0, bfr[j], acc[2*ip][j], 0, 0, 0);
          acc[2*ip+1][j] = __builtin_amdgcn_mfma_f32_16x16x32_bf16(af1, bfr[j], acc[2*ip+1][j], 0, 0, 0);
        }
      }
    }
  }

  // ---- phase 1.5: + prep gather, LN stats, normalize+ReLU, u -> LDS (swizzled) ----
  int gb = (m0 / NPTS) * NG;
  #pragma unroll
  for (int i = 0; i < 8; ++i){
    #pragma unroll
    for (int r = 0; r < 4; ++r){
      int row = (i<<4) + (l4<<2) + r;
      int grp = gb + glab_s[row];
      #pragma unroll
      for (int j = 0; j < 2; ++j){
        int n = (w<<5) + (j<<4) + l15;
        acc[i][j][r] += prepf[((size_t)grp << 9) + n];
      }
    }
  }
  #pragma unroll
  for (int i = 0; i < 8; ++i)
    #pragma unroll
    for (int r = 0; r < 4; ++r){
      float s = 0.f, q = 0.f;
      #pragma unroll
      for (int j = 0; j < 2; ++j){ float v = acc[i][j][r]; s += v; q += v*v; }
      #pragma unroll
      for (int mk = 1; mk < 16; mk <<= 1){ s += __shfl_xor(s, mk); q += __shfl_xor(q, mk); }
      if (l15 == 0){
        int row = (i<<4) + (l4<<2) + r;
        atomicAdd(&ssum[row], s);
        atomicAdd(&ssq[row], q);
      }
    }
  __syncthreads();   // also: all h reads complete
  if (tid < 128){
    float mu = ssum[tid] * (1.f/512.f);
    float var = ssq[tid] * (1.f/512.f) - mu*mu;
    ssum[tid] = mu;
    ssq[tid] = rsqrtf(var + 1e-5f);
  }
  __syncthreads();
  {
    float gcol[2], bcol[2];
    #pragma unroll
    for (int j = 0; j < 2; ++j){
      int n = (w<<5) + (j<<4) + l15;
      gcol[j] = g2[n]; bcol[j] = beta2[n];
    }
    #pragma unroll
    for (int i = 0; i < 8; ++i)
      #pragma unroll
      for (int r = 0; r < 4; ++r){
        int row = (i<<4) + (l4<<2) + r;
        float mu = ssum[row], inv = ssq[row];
        #pragma unroll
        for (int j = 0; j < 2; ++j){
          int n = (w<<5) + (j<<4) + l15;
          float v = fmaxf((acc[i][j][r] - mu)*inv*gcol[j] + bcol[j], 0.f);
          int byo = (row << 10) + (((n << 1)) ^ ((row & 7) << 4));
          *(u16*)(smem + byo) = f2bf_bits(v);
        }
      }
  }
  __syncthreads();   // u complete

  // ---- phase 2 (barrier-free): v = u_lds @ w2b; per wave 128 rows x 16 cols ----
  f32x4 acc2[8];
  #pragma unroll
  for (int i = 0; i < 8; ++i)
    #pragma unroll
    for (int e = 0; e < 4; ++e) acc2[i][e] = 0.f;

  {
    const u16* wB = wt2b + ((size_t)((w<<4) + l15))*512 + l4*8;  // + k
    #pragma unroll
    for (int kk = 0; kk < 16; ++kk){
      const int k0 = kk*32;
      bf16x8 bf2 = *(const bf16x8*)(wB + k0);
      #pragma unroll
      for (int ip = 0; ip < 4; ++ip){
        bf16x8 af0, af1;
        {
          int row0 = ((2*ip)<<4) + l15;
          int row1 = ((2*ip+1)<<4) + l15;
          af0 = *(const bf16x8*)(smem + (row0 << 10) + ((((k0 + l4*8)) << 1) ^ ((row0 & 7) << 4)));
          af1 = *(const bf16x8*)(smem + (row1 << 10) + ((((k0 + l4*8)) << 1) ^ ((row1 & 7) << 4)));
        }
        acc2[2*ip]   = __builtin_amdgcn_mfma_f32_16x16x32_bf16(af0, bf2, acc2[2*ip], 0, 0, 0);
        acc2[2*ip+1] = __builtin_amdgcn_mfma_f32_16x16x32_bf16(af1, bf2, acc2[2*ip+1], 0, 0, 0);
      }
    }
  }
  __syncthreads();   // all u reads done before vbuf overwrite

  // ---- epilogue: v -> vbuf [128][256] f32 (aliases u), 32-row-quarter segment walks ----
  float bb = b2b[(w<<4) + l15];
  float* vbuf = (float*)smem;
  #pragma unroll
  for (int i = 0; i < 8; ++i){
    int n = (w<<4) + l15;
    #pragma unroll
    for (int r = 0; r < 4; ++r){
      int row = (i<<4) + (l4<<2) + r;
      vbuf[row*256 + n] = acc2[i][r] + bb;
    }
  }
  __syncthreads();
  {
    int c = tid & 255;
    int q = tid >> 8;                 // quarter 0..3 (32 rows each)
    int r0 = q << 5;
    size_t qblk = ((size_t)blockIdx.x << 2) + q;   // absolute 32-row chunk id
    int curg = glab_s[r0];
    float mx = vbuf[r0*256 + c];
    bool from0 = true;
    for (int r = 1; r < 32; ++r){
      int g = glab_s[r0 + r];
      float v = vbuf[(r0 + r)*256 + c];
      if (g != curg){
        if (from0) pf[qblk*256 + c] = mx;
        else       dstage[((size_t)(gb + curg))*256 + c] = mx;
        curg = g; mx = v; from0 = false;
      } else mx = fmaxf(mx, v);
    }
    if (from0) pf[qblk*256 + c] = mx;
    else       pl[qblk*256 + c] = mx;
  }
}

// ---------------- combine: out[bg] = max over 32-row-chunk partials (deterministic) ----------------
__global__ __launch_bounds__(256) void k_combine(const int* __restrict__ offs,
                                                 const int* __restrict__ counts,
                                                 const float* __restrict__ pf,
                                                 const float* __restrict__ pl,
                                                 const float* __restrict__ dstage,
                                                 float* __restrict__ outp){
  int bg = blockIdx.x, c = threadIdx.x;
  int cnt = counts[bg];
  if (cnt == 0){ outp[(size_t)bg*256 + c] = 0.f; return; }
  int off = offs[bg], end = off + cnt;
  int B0 = off >> 5, B1 = (end - 1) >> 5;
  float v;
  if (B0 == B1){
    if ((off & 31) == 0)      v = pf[(size_t)B0*256 + c];
    else if ((end & 31) == 0) v = pl[(size_t)B0*256 + c];
    else                      v = dstage[(size_t)bg*256 + c];
  } else {
    v = ((off & 31) == 0) ? pf[(size_t)B0*256 + c] : pl[(size_t)B0*256 + c];
    for (int k = B0 + 1; k <= B1; ++k)
      v = fmaxf(v, pf[(size_t)k*256 + c]);
  }
  outp[(size_t)bg*256 + c] = v;
}

// ---------------- ws-too-small signal ----------------
__global__ void k_sig(float* __restrict__ out, float val){
  int i = blockIdx.x*blockDim.x + threadIdx.x;
  if (i < 256) out[i] = val;
}

extern "C" void kernel_launch(void* const* d_in, const int* in_sizes, int n_in,
                              void* d_out, int out_size, void* d_ws, size_t ws_size,
                              hipStream_t stream) {
  const float* xyz    = (const float*)d_in[0];
  const int*   labels = (const int*)  d_in[1];
  const float* w1a    = (const float*)d_in[2];
  const float* b1a    = (const float*)d_in[3];
  const float* g1     = (const float*)d_in[4];
  const float* beta1  = (const float*)d_in[5];
  const float* w1b    = (const float*)d_in[6];
  const float* b1b    = (const float*)d_in[7];
  const float* w2a    = (const float*)d_in[8];
  const float* b2a    = (const float*)d_in[9];
  const float* g2     = (const float*)d_in[10];
  const float* beta2  = (const float*)d_in[11];
  const float* w2b    = (const float*)d_in[12];
  const float* b2b    = (const float*)d_in[13];
  float* out = (float*)d_out;
  char* ws = (char*)d_ws;

  if (ws_size < WS_NEED){
    k_sig<<<1, 256, 0, stream>>>(out, 10000.f + (float)(ws_size >> 20));
    return;
  }

  float*     sums   = (float*)(ws + WS_SUMS);
  u16*       a1     = (u16*)(ws + WS_A1);
  u16*       h      = (u16*)(ws + WS_H);
  u16*       poolbf = (u16*)(ws + WS_PBF);
  u16*       wt1    = (u16*)(ws + WS_WT1);
  u16*       wt2a   = (u16*)(ws + WS_WT2A);
  u16*       wt2b   = (u16*)(ws + WS_WT2B);
  float*     prepf  = (float*)(ws + WS_PREP);
  int*       offs   = (int*)(ws + WS_OFFS);
  int*       counts = (int*)(ws + WS_CNT);
  int*       cursor = (int*)(ws + WS_CUR);
  int*       sortpos= (int*)(ws + WS_SPOS);
  int*       glab   = (int*)(ws + WS_GLAB);
  float*     pf     = (float*)(ws + WS_PF);
  float*     pl     = (float*)(ws + WS_PL);
  float*     dstage = (float*)(ws + WS_DST);

  float* cent_out = out + OFF_CENT;
  float* out_seg  = out + OFF_OUT;
  float* pi_out   = out + OFF_PI;
  float* lab_out  = out + OFF_LAB;

  k_init<<<64, 256, 0, stream>>>(sums, cursor);
  k_wt<<<(128*256+255)/256, 256, 0, stream>>>(w1b, wt1, 128, 256);
  k_wt<<<(512*512+255)/256, 256, 0, stream>>>(w2a, wt2a, 512, 512);
  k_wt<<<(512*256+255)/256, 256, 0, stream>>>(w2b, wt2b, 512, 256);
  k_points<<<NP/256, 256, 0, stream>>>(xyz, labels, sums, lab_out);
  k_cent<<<(NB_*NG+255)/256, 256, 0, stream>>>(sums, cent_out);
  k_scan<<<NB_, 256, 0, stream>>>(sums, offs, counts);
  k_scatter<<<NP/256, 256, 0, stream>>>(labels, offs, cursor, sortpos, glab);
  k_mlp1<<<NP/4, 256, 0, stream>>>(xyz, labels, sortpos, cent_out,
                                   w1a, b1a, g1, beta1, a1, pi_out);
  // GEMM1: h = a1 @ w1b + b1b (sorted rows); bf16 store
  mgemm<1><<<(NP/128)*(256/128), 256, 0, stream>>>(
      a1, 128, 128, wt1, 128, 0, b1b, h, (float*)nullptr, 256, 256);
  // pool: per-group max over sorted h -> poolbf
  k_pool<<<NB_*NG, 256, 0, stream>>>(h, offs, counts, poolbf);
  // prep = poolbf @ w2a[0:256,:] + b2a : [B*G, 512] f32
  mgemm<3><<<(NB_*NG/128)*(512/128), 256, 0, stream>>>(
      poolbf, 256, 256, wt2a, 512, 0, b2a, (u16*)nullptr, prepf, 512, 512);
  // fused6: GEMM2a' + LN + GEMM2b -> 32-row-chunk partial maxes
  fused6<<<NBLK, 1024, 0, stream>>>(h, wt2a, wt2b, prepf, b2b, g2, beta2, glab,
                                    pf, pl, dstage);
  // combine partials -> out
  k_combine<<<NB_*NG, 256, 0, stream>>>(offs, counts, pf, pl, dstage, out_seg);
}